// Round 7
// baseline (589.402 us; speedup 1.0000x reference)
//
#include <hip/hip_runtime.h>
#include <math.h>

#define I_SZ   4096
#define H_SZ   3584
#define O_SZ   512
#define TOTAL  8192
#define HO     4096   // TOTAL - I_SZ (rows that actually update)
#define BETA   0.1f
#define LR     0.5f
#define T1C    20
#define T2C    4

#define NBLK   512    // persistent grid: 2 blocks/CU on 256 CUs
#define NTHR   1024   // 16 waves; 8 rows/block, 2 waves/row
#define GSH    6      // 64 blocks per barrier group
#define NGRP   8      // 8 groups

// ---------------- tiny pre-kernel: bar zero + out[0:I]=x + te/tsum ----------------
__global__ void k_pre(const float* __restrict__ x, const float* __restrict__ target,
                      const float* __restrict__ mask, float* __restrict__ out,
                      float* __restrict__ te, float* __restrict__ tsum,
                      unsigned int* __restrict__ bar) {
    __shared__ float red[8];
    int t = threadIdx.x;                  // 1024
    bar[t] = 0u;
    #pragma unroll
    for (int m = 0; m < 4; m++) out[t + 1024 * m] = x[t + 1024 * m];
    if (t < 512) {
        float v = mask[t] * target[t];
        te[t] = v;
        float z = v;
        for (int off = 32; off > 0; off >>= 1) z += __shfl_down(z, off, 64);
        if ((t & 63) == 0) red[t >> 6] = z;
    }
    __syncthreads();
    if (t == 0) { float s = 0.f; for (int i = 0; i < 8; i++) s += red[i]; tsum[0] = s; }
}

// ---------------- grid barrier (hierarchical, relaxed agent atomics) ----------------
// bar layout (uints): cnt[g] at bar[g*64] (g=0..7), gcnt at bar[512],
// per-group release flags at bar[576 + g*32].
__device__ __forceinline__ void grid_barrier(unsigned int* bar, int blk, int tid,
                                             unsigned int e) {
    __syncthreads();   // drains vmcnt: all agent stores complete at coherence point
    if (tid == 0) {
        unsigned int g = (unsigned int)blk >> GSH;   // 0..7
        unsigned int v = __hip_atomic_fetch_add(&bar[g * 64], 1u, __ATOMIC_RELAXED,
                                                __HIP_MEMORY_SCOPE_AGENT);
        if (v == e * 64u - 1u) {
            unsigned int v2 = __hip_atomic_fetch_add(&bar[512], 1u, __ATOMIC_RELAXED,
                                                     __HIP_MEMORY_SCOPE_AGENT);
            if (v2 == e * (unsigned int)NGRP - 1u) {
                #pragma unroll
                for (int q = 0; q < NGRP; ++q)
                    __hip_atomic_store(&bar[576 + q * 32], e, __ATOMIC_RELAXED,
                                       __HIP_MEMORY_SCOPE_AGENT);
            }
        }
        while (__hip_atomic_load(&bar[576 + g * 32], __ATOMIC_RELAXED,
                                 __HIP_MEMORY_SCOPE_AGENT) < e)
            __builtin_amdgcn_s_sleep(1);
    }
    __syncthreads();
}

// ---------------- persistent kernel: setup + all 24 steps, zero intermediates -------
// R7: R6 still spilled w0..w15 ONCE in the panel phase (VGPR budget is hard-pinned
// at 64; 86 MB scratch WRITE_SIZE). Fix: SPLIT EACH ROW ACROSS 2 WAVES -- 8 rows/
// block, 512 blocks, each lane holds 8 float4 (32 VGPRs). Setup working set now
// fits the 64-VGPR budget by construction; launch_bounds(1024,8) makes it explicit
// and guarantees 2-block/CU co-residency (LDS ~50 KB). Per-iteration cross-wave
// combine via red[]+syncthreads. Chunked XCD swizzle keeps adjacent 8-column
// panel slices (shared cachelines) on the same XCD L2.
__global__ void __launch_bounds__(NTHR, 8) k_run(
    const float* __restrict__ W, const float* __restrict__ x,
    const float* __restrict__ te, const float* __restrict__ tsum,
    float* __restrict__ s_a, float* __restrict__ s_b,
    unsigned int* __restrict__ bar)
{
    const int blk  = blockIdx.x;
    const int lblk = (blk & 7) * 64 + (blk >> 3);   // bijective chunked XCD swizzle
    const int tid  = threadIdx.x;
    const int wave = tid >> 6;          // 0..15
    const int rl   = wave >> 1;         // row-local 0..7
    const int h    = wave & 1;          // half of the row
    const int lane = tid & 63;
    const int li   = h * 64 + lane;     // 0..127: lane within the row pair
    const int row  = lblk * 8 + rl;     // 0..HO-1
    const bool out_blk = (lblk >= H_SZ / 8);   // rows >= 3584

    __shared__ float panT[8][1028];     // ~32 KB transpose panel (startup only)
    __shared__ float sh[HO];            // staged s_tail (16 KB)
    __shared__ float red[16];

    // ---- row part: w0..w7 = right half of W[I+row]; b1 partial from left half ----
    const float*  Wrow = W + (size_t)(I_SZ + row) * TOTAL;
    const float4* wr4  = (const float4*)(Wrow + I_SZ);
    const float4* wl4  = (const float4*)Wrow;
    const float4* x4   = (const float4*)x;
    float bvacc = 0.0f;
    float4 w0, w1, w2, w3, w4, w5, w6, w7;

#define LOADW(K) { w##K = wr4[li + 128 * (K)];                                   \
    float4 a_ = wl4[li + 128 * (K)]; float4 b_ = x4[li + 128 * (K)];             \
    bvacc += a_.x * b_.x + a_.y * b_.y + a_.z * b_.z + a_.w * b_.w; }
    LOADW(0) LOADW(1) LOADW(2) LOADW(3)
    LOADW(4) LOADW(5) LOADW(6) LOADW(7)
#undef LOADW

    // ---- column panels: 8 chunks of 1024 rows of W, columns I+lblk*8 .. +7 ----
    // Load 4 cols per float4 (2 loads/thread), store transposed into panT.
#define PANEL(P) {                                                               \
    for (int m_ = 0; m_ < 2; ++m_) {                                             \
        int idx_ = tid + 1024 * m_;          /* 0..2047 */                       \
        int j_   = idx_ >> 1;                /* 0..1023 */                       \
        int hf_  = idx_ & 1;                                                     \
        const float4 v_ = *(const float4*)(W + (size_t)((P) * 1024 + j_) * TOTAL \
                                           + (I_SZ + lblk * 8 + hf_ * 4));       \
        panT[hf_ * 4 + 0][j_] = v_.x; panT[hf_ * 4 + 1][j_] = v_.y;              \
        panT[hf_ * 4 + 2][j_] = v_.z; panT[hf_ * 4 + 3][j_] = v_.w;              \
    }                                                                            \
    __syncthreads(); }

    // chunks 0..3 (j < I_SZ): dot with x -> b2 half of bv
#define BVP(P) PANEL(P) {                                                        \
    const float4* pr_ = (const float4*)(&panT[rl][0]);                           \
    float4 p0_ = pr_[li],  p1_ = pr_[li + 128];                                  \
    float4 xa_ = x4[(P) * 256 + li], xb_ = x4[(P) * 256 + li + 128];             \
    bvacc += p0_.x * xa_.x + p0_.y * xa_.y + p0_.z * xa_.z + p0_.w * xa_.w;      \
    bvacc += p1_.x * xb_.x + p1_.y * xb_.y + p1_.z * xb_.z + p1_.w * xb_.w;      \
    } __syncthreads();

    BVP(0) BVP(1) BVP(2) BVP(3)
#undef BVP

    // chunks 4..7 (j >= I_SZ): symmetrize into named regs (static indices only)
#define SYMP(P, KA, KB) PANEL(P) {                                               \
    const float4* pr_ = (const float4*)(&panT[rl][0]);                           \
    float4 pa_ = pr_[li], pb_ = pr_[li + 128];                                   \
    w##KA.x = 0.5f * (w##KA.x + pa_.x); w##KA.y = 0.5f * (w##KA.y + pa_.y);      \
    w##KA.z = 0.5f * (w##KA.z + pa_.z); w##KA.w = 0.5f * (w##KA.w + pa_.w);      \
    w##KB.x = 0.5f * (w##KB.x + pb_.x); w##KB.y = 0.5f * (w##KB.y + pb_.y);      \
    w##KB.z = 0.5f * (w##KB.z + pb_.z); w##KB.w = 0.5f * (w##KB.w + pb_.w);      \
    } __syncthreads();

    SYMP(4, 0, 1)
    SYMP(5, 2, 3)
    SYMP(6, 4, 5)
    SYMP(7, 6, 7)
#undef SYMP
#undef PANEL

    // ---- bv = 0.5*(b1 + b2): wave reduce, then cross-wave pair combine ----
    for (int off = 32; off > 0; off >>= 1) bvacc += __shfl_down(bvacc, off, 64);
    if (lane == 0) red[wave] = bvacc;
    __syncthreads();
    float bvrow = 0.0f;
    if (h == 0 && lane == 0) bvrow = 0.5f * (red[wave] + red[wave + 1]);
    __syncthreads();

    const float ts  = tsum[0];
    const float tev = (row >= H_SZ) ? te[row - H_SZ] : 0.0f;

    // ---- iteration 0: s_tail = 0 -> g = bv, s_row = 0 (no staging, no dot) ----
    if (h == 0 && lane == 0) {
        float nv = tanhf(-LR * bvrow);
        __hip_atomic_store(&s_b[I_SZ + row], nv, __ATOMIC_RELAXED,
                           __HIP_MEMORY_SCOPE_AGENT);
    }
    grid_barrier(bar, blk, tid, 1u);

    for (int it = 1; it < T1C + T2C; ++it) {
        const float* cur = (it & 1) ? s_b : s_a;
        float*       nxt = (it & 1) ? s_a : s_b;
        const bool betap = (it >= T1C);

        // ---- stage s_tail -> LDS through the coherence point (agent-scope 8B loads)
        const unsigned long long* cu = (const unsigned long long*)(cur + I_SZ);
        unsigned long long* shu = (unsigned long long*)sh;
        #pragma unroll
        for (int m = 0; m < 2; ++m) {
            int idx = tid + NTHR * m;         // < 2048
            shu[idx] = __hip_atomic_load(&cu[idx], __ATOMIC_RELAXED,
                                         __HIP_MEMORY_SCOPE_AGENT);
        }
        __syncthreads();

        const float4* sh4 = (const float4*)sh;

        // ---- wave-local softmax stats (beta phase, h==0 waves of output rows) ----
        float sm_m = 0.f, sm_z = 1.f;
        if (betap && out_blk && h == 0) {
            float4 l0 = sh4[H_SZ / 4 + lane];
            float4 l1 = sh4[H_SZ / 4 + 64 + lane];
            float m = fmaxf(fmaxf(fmaxf(l0.x, l0.y), fmaxf(l0.z, l0.w)),
                            fmaxf(fmaxf(l1.x, l1.y), fmaxf(l1.z, l1.w)));
            for (int off = 32; off > 0; off >>= 1) m = fmaxf(m, __shfl_xor(m, off, 64));
            float z = expf(l0.x - m) + expf(l0.y - m) + expf(l0.z - m) + expf(l0.w - m)
                    + expf(l1.x - m) + expf(l1.y - m) + expf(l1.z - m) + expf(l1.w - m);
            for (int off = 32; off > 0; off >>= 1) z += __shfl_xor(z, off, 64);
            sm_m = m; sm_z = z;
        }

        // ---- 2 waves per row: 2048-wide partial dot each, combine via LDS ----
        float acc = 0.0f;
#define DOT(K) { float4 s_ = sh4[li + 128 * (K)];                                \
    acc += w##K.x * s_.x + w##K.y * s_.y + w##K.z * s_.z + w##K.w * s_.w; }
        DOT(0) DOT(1) DOT(2) DOT(3)
        DOT(4) DOT(5) DOT(6) DOT(7)
#undef DOT
        for (int off = 32; off > 0; off >>= 1) acc += __shfl_down(acc, off, 64);
        if (lane == 0) red[wave] = acc;
        __syncthreads();
        if (h == 0 && lane == 0) {
            float g = red[wave] + red[wave + 1] + bvrow;
            if (betap && out_blk) {
                float p = expf(sh[row] - sm_m) / sm_z;
                g += -BETA * (p * ts - tev);
            }
            float nv = tanhf(sh[row] - LR * g);
            __hip_atomic_store(&nxt[I_SZ + row], nv, __ATOMIC_RELAXED,
                               __HIP_MEMORY_SCOPE_AGENT);
        }

        // ---- last iteration: stores drain at kernel end; no consumer inside ----
        if (it == T1C + T2C - 1) break;
        grid_barrier(bar, blk, tid, (unsigned int)(it + 1));
    }
}

// ================= fallback path (only if cooperative launch fails) =================
__global__ void k_init_fb(const float* __restrict__ x, float* __restrict__ s_a,
                          float* __restrict__ s_b, unsigned int* __restrict__ bar) {
    int i = blockIdx.x * 256 + threadIdx.x;
    if (i < I_SZ) { float v = x[i]; s_a[i] = v; s_b[i] = v; }
    else if (i < TOTAL) { s_a[i] = 0.0f; }
    if (i < 1024) bar[i] = 0u;
}

__global__ void k_build_wt(const float* __restrict__ W, float* __restrict__ Wt) {
    int bj = blockIdx.x, bi = blockIdx.y;
    if (bi > bj) return;
    __shared__ float ta[32][33], tb[32][33];
    int tx = threadIdx.x;
    int ty = threadIdx.y;
    int r0 = bi * 32, c0 = bj * 32;
    #pragma unroll
    for (int k = 0; k < 4; k++) {
        int a = ty + 8 * k;
        ta[a][tx] = W[(size_t)(I_SZ + r0 + a) * TOTAL + (I_SZ + c0 + tx)];
    }
    if (bi != bj) {
        #pragma unroll
        for (int k = 0; k < 4; k++) {
            int a = ty + 8 * k;
            tb[a][tx] = W[(size_t)(I_SZ + c0 + a) * TOTAL + (I_SZ + r0 + tx)];
        }
    }
    __syncthreads();
    if (bi == bj) {
        #pragma unroll
        for (int k = 0; k < 4; k++) {
            int a = ty + 8 * k;
            Wt[(size_t)(r0 + a) * HO + (c0 + tx)] = 0.5f * (ta[a][tx] + ta[tx][a]);
        }
    } else {
        #pragma unroll
        for (int k = 0; k < 4; k++) {
            int a = ty + 8 * k;
            Wt[(size_t)(r0 + a) * HO + (c0 + tx)] = 0.5f * (ta[a][tx] + tb[tx][a]);
            Wt[(size_t)(c0 + a) * HO + (r0 + tx)] = 0.5f * (tb[a][tx] + ta[tx][a]);
        }
    }
}

__global__ void k_build_b1(const float* __restrict__ W, const float* __restrict__ x,
                           float* __restrict__ bvec) {
    int r = blockIdx.x;
    int t = threadIdx.x;
    const float4* wrow = (const float4*)(W + (size_t)(I_SZ + r) * TOTAL);
    const float4* xv   = (const float4*)x;
    float acc = 0.0f;
    #pragma unroll
    for (int k = 0; k < 4; k++) {
        int idx = t + 256 * k;
        float4 w  = wrow[idx];
        float4 s4 = xv[idx];
        acc += w.x * s4.x + w.y * s4.y + w.z * s4.z + w.w * s4.w;
    }
    __shared__ float red[4];
    for (int off = 32; off > 0; off >>= 1) acc += __shfl_down(acc, off, 64);
    if ((t & 63) == 0) red[t >> 6] = acc;
    __syncthreads();
    if (t == 0) bvec[r] = 0.5f * (red[0] + red[1] + red[2] + red[3]);
}

__global__ void k_build_b2(const float* __restrict__ W, const float* __restrict__ x,
                           float* __restrict__ bvec) {
    int c  = blockIdx.x * 256 + threadIdx.x;
    int j0 = blockIdx.y * 64;
    float acc = 0.0f;
    for (int j = j0; j < j0 + 64; j++)
        acc += W[(size_t)j * TOTAL + (I_SZ + c)] * x[j];
    atomicAdd(&bvec[c], 0.5f * acc);
}

template <bool BETA_STEP>
__global__ void __launch_bounds__(256, 4) k_step4(
    const float* __restrict__ Wt, const float* __restrict__ bvec,
    const float* __restrict__ s_cur, float* __restrict__ s_next,
    const float* __restrict__ te, const float* __restrict__ tsum)
{
    const int blk  = blockIdx.x;
    const int t    = threadIdx.x;
    const int wave = t >> 6;
    const int lane = t & 63;
    const int row  = blk * 4 + wave;

    __shared__ float red[4];
    __shared__ float sm_m, sm_z;

    if (BETA_STEP && blk >= H_SZ / 4) {
        float l0 = s_cur[I_SZ + H_SZ + t];
        float l1 = s_cur[I_SZ + H_SZ + t + 256];
        float m = fmaxf(l0, l1);
        for (int off = 32; off > 0; off >>= 1) m = fmaxf(m, __shfl_down(m, off, 64));
        if (lane == 0) red[wave] = m;
        __syncthreads();
        if (t == 0) sm_m = fmaxf(fmaxf(red[0], red[1]), fmaxf(red[2], red[3]));
        __syncthreads();
        float z = expf(l0 - sm_m) + expf(l1 - sm_m);
        for (int off = 32; off > 0; off >>= 1) z += __shfl_down(z, off, 64);
        if (lane == 0) red[wave] = z;
        __syncthreads();
        if (t == 0) sm_z = red[0] + red[1] + red[2] + red[3];
        __syncthreads();
    }

    const float4* w4 = (const float4*)(Wt + (size_t)row * HO);
    const float4* s4 = (const float4*)(s_cur + I_SZ);
    float4 w[16];
    #pragma unroll
    for (int k = 0; k < 16; k++) w[k] = w4[lane + 64 * k];
    float acc = 0.0f;
    #pragma unroll
    for (int k = 0; k < 16; k++) {
        float4 s = s4[lane + 64 * k];
        acc += w[k].x * s.x + w[k].y * s.y + w[k].z * s.z + w[k].w * s.w;
    }
    for (int off = 32; off > 0; off >>= 1) acc += __shfl_down(acc, off, 64);
    if (lane == 0) {
        float g = acc + bvec[row];
        if (BETA_STEP && row >= H_SZ) {
            int j = row - H_SZ;
            float p = expf(s_cur[I_SZ + H_SZ + j] - sm_m) / sm_z;
            g += -BETA * (p * tsum[0] - te[j]);
        }
        int i = I_SZ + row;
        s_next[i] = tanhf(s_cur[i] - LR * g);
    }
}

extern "C" void kernel_launch(void* const* d_in, const int* in_sizes, int n_in,
                              void* d_out, int out_size, void* d_ws, size_t ws_size,
                              hipStream_t stream) {
    const float* W      = (const float*)d_in[0];
    const float* x      = (const float*)d_in[1];
    const float* target = (const float*)d_in[2];
    const float* mask   = (const float*)d_in[3];
    float* out = (float*)d_out;   // state buffer A (24 steps even -> final lands here)
    char*  ws  = (char*)d_ws;

    const size_t WS_WT = (size_t)HO * HO * sizeof(float);   // 64 MB (fallback only)
    float*        Wt   = (float*)ws;
    float*        bvec = (float*)(ws + WS_WT);
    float*        te   = bvec + HO;
    float*        tsum = te + O_SZ;
    float*        s_b  = tsum + 64;
    unsigned int* bar  = (unsigned int*)(s_b + TOTAL + 64);

    k_pre<<<1, 1024, 0, stream>>>(x, target, mask, out, te, tsum, bar);

    void* args[] = { (void*)&W, (void*)&x, (void*)&te, (void*)&tsum,
                     (void*)&out, (void*)&s_b, (void*)&bar };
    hipError_t err = hipLaunchCooperativeKernel((const void*)k_run, dim3(NBLK), dim3(NTHR),
                                                args, 0, stream);
    if (err != hipSuccess) {
        // fallback: known-good multi-dispatch chain
        k_init_fb<<<(TOTAL + 255) / 256, 256, 0, stream>>>(x, out, s_b, bar);
        k_build_wt<<<dim3(HO / 32, HO / 32), dim3(32, 8), 0, stream>>>(W, Wt);
        k_build_b1<<<HO, 256, 0, stream>>>(W, x, bvec);
        k_build_b2<<<dim3(HO / 256, I_SZ / 64), 256, 0, stream>>>(W, x, bvec);
        const float* cur = out;
        float* nxt = s_b;
        for (int it = 0; it < T1C + T2C; it++) {
            if (it >= T1C) {
                k_step4<true><<<HO / 4, 256, 0, stream>>>(Wt, bvec, cur, nxt, te, tsum);
            } else {
                k_step4<false><<<HO / 4, 256, 0, stream>>>(Wt, bvec, cur, nxt, te, tsum);
            }
            float* tmp = (float*)cur; cur = nxt; nxt = tmp;
        }
    }
}

// Round 8
// 514.814 us; speedup vs baseline: 1.1449x; 1.1449x over previous
//
#include <hip/hip_runtime.h>
#include <math.h>

#define I_SZ   4096
#define H_SZ   3584
#define O_SZ   512
#define TOTAL  8192
#define HO     4096   // TOTAL - I_SZ (rows that actually update)
#define BETA   0.1f
#define LR     0.5f
#define T1C    20
#define T2C    4

#define NBLK   256    // persistent grid: 1 block/CU on 256 CUs
#define NTHR   1024   // 16 waves -> 16 rows/block, 1 row/wave
#define GSH    5      // 32 blocks per barrier group
#define NGRP   8      // 8 groups

// ---------------- tiny pre-kernel: bar zero + out[0:I]=x + te/tsum ----------------
__global__ void k_pre(const float* __restrict__ x, const float* __restrict__ target,
                      const float* __restrict__ mask, float* __restrict__ out,
                      float* __restrict__ te, float* __restrict__ tsum,
                      unsigned int* __restrict__ bar) {
    __shared__ float red[8];
    int t = threadIdx.x;                  // 1024
    bar[t] = 0u;
    #pragma unroll
    for (int m = 0; m < 4; m++) out[t + 1024 * m] = x[t + 1024 * m];
    if (t < 512) {
        float v = mask[t] * target[t];
        te[t] = v;
        float z = v;
        for (int off = 32; off > 0; off >>= 1) z += __shfl_down(z, off, 64);
        if ((t & 63) == 0) red[t >> 6] = z;
    }
    __syncthreads();
    if (t == 0) { float s = 0.f; for (int i = 0; i < 8; i++) s += red[i]; tsum[0] = s; }
}

// ---------------- grid barrier (hierarchical, relaxed agent atomics) ----------------
// bar layout (uints): cnt[g] at bar[g*64] (g=0..7), gcnt at bar[512],
// per-group release flags at bar[576 + g*32].
__device__ __forceinline__ void grid_barrier(unsigned int* bar, int blk, int tid,
                                             unsigned int e) {
    __syncthreads();   // drains vmcnt: all agent stores complete at coherence point
    if (tid == 0) {
        unsigned int g = (unsigned int)blk >> GSH;   // 0..7
        unsigned int v = __hip_atomic_fetch_add(&bar[g * 64], 1u, __ATOMIC_RELAXED,
                                                __HIP_MEMORY_SCOPE_AGENT);
        if (v == e * 32u - 1u) {
            unsigned int v2 = __hip_atomic_fetch_add(&bar[512], 1u, __ATOMIC_RELAXED,
                                                     __HIP_MEMORY_SCOPE_AGENT);
            if (v2 == e * (unsigned int)NGRP - 1u) {
                #pragma unroll
                for (int q = 0; q < NGRP; ++q)
                    __hip_atomic_store(&bar[576 + q * 32], e, __ATOMIC_RELAXED,
                                       __HIP_MEMORY_SCOPE_AGENT);
            }
        }
        while (__hip_atomic_load(&bar[576 + g * 32], __ATOMIC_RELAXED,
                                 __HIP_MEMORY_SCOPE_AGENT) < e)
            __builtin_amdgcn_s_sleep(1);
    }
    __syncthreads();
}

// ---------------- persistent kernel: setup + all 24 steps, zero intermediates -------
// R8: R6 structure (1 row/wave, named w0..w15 = 64 VGPRs) with the VGPR budget
// FIXED. Empirical launch_bounds curve on this toolchain (1024-thread blocks):
// arg=4 -> 64 VGPRs (R6, spilled once, 86 MB scratch), arg=8 -> 32 (R7, spilled
// everything, 129 MB). arg=1 -> budget 128 (the hard cap for a 16-wave block:
// 4 waves/SIMD x 512-VGPR pool). 64 w-regs + ~40 body <= 128 -> no spill.
// lblk: bijective chunked XCD swizzle -- each XCD's 32 blocks own a contiguous
// 512-column panel slice so 64 B half-line panel reads share the same XCD L2.
__global__ void __launch_bounds__(NTHR, 1) k_run(
    const float* __restrict__ W, const float* __restrict__ x,
    const float* __restrict__ te, const float* __restrict__ tsum,
    float* __restrict__ s_a, float* __restrict__ s_b,
    unsigned int* __restrict__ bar)
{
    const int blk  = blockIdx.x;
    const int lblk = (blk & 7) * 32 + (blk >> 3);   // bijective for 256 blocks
    const int tid  = threadIdx.x;
    const int wave = tid >> 6;
    const int lane = tid & 63;
    const int row  = lblk * 16 + wave;        // 0..HO-1
    const bool out_block = (lblk >= H_SZ / 16);

    __shared__ float panT[16][1028];          // 64 KB+pad transpose panel (startup only)
    __shared__ float sh[HO];                  // staged s_tail (16 KB)

    // ---- row part: wK = W[I+row][I_SZ + ...] ; b1 partial from left half ----
    const float*  Wrow = W + (size_t)(I_SZ + row) * TOTAL;
    const float4* wr4  = (const float4*)(Wrow + I_SZ);
    const float4* wl4  = (const float4*)Wrow;
    const float4* x4   = (const float4*)x;
    float bvacc = 0.0f;
    float4 w0, w1, w2, w3, w4, w5, w6, w7, w8, w9, w10, w11, w12, w13, w14, w15;

#define LOADW(K) { w##K = wr4[lane + 64 * (K)];                                  \
    float4 a_ = wl4[lane + 64 * (K)]; float4 b_ = x4[lane + 64 * (K)];           \
    bvacc += a_.x * b_.x + a_.y * b_.y + a_.z * b_.z + a_.w * b_.w; }
    LOADW(0)  LOADW(1)  LOADW(2)  LOADW(3)
    LOADW(4)  LOADW(5)  LOADW(6)  LOADW(7)
    LOADW(8)  LOADW(9)  LOADW(10) LOADW(11)
    LOADW(12) LOADW(13) LOADW(14) LOADW(15)
#undef LOADW

    // ---- column panels: 8 chunks of 1024 rows of W, columns I+lblk*16 .. +15 ----
#define PANEL(P) {                                                               \
    for (int m_ = 0; m_ < 4; ++m_) {                                             \
        int idx_ = tid + 1024 * m_;          /* 0..4095 */                       \
        int cl_  = idx_ >> 2;                /* j within chunk */                \
        int j4_  = (idx_ & 3) * 4;           /* 0,4,8,12 */                      \
        const float4 v_ = *(const float4*)(W + (size_t)((P) * 1024 + cl_) * TOTAL \
                                           + (I_SZ + lblk * 16 + j4_));          \
        panT[j4_ + 0][cl_] = v_.x; panT[j4_ + 1][cl_] = v_.y;                    \
        panT[j4_ + 2][cl_] = v_.z; panT[j4_ + 3][cl_] = v_.w;                    \
    }                                                                            \
    __syncthreads(); }

    // chunks 0..3 (j < I_SZ): dot with x -> b2 half of bv
#define BVP(P) PANEL(P) {                                                        \
    const float4* pr_ = (const float4*)(&panT[wave][0]);                         \
    for (int kk_ = 0; kk_ < 4; ++kk_) {                                          \
        float4 pv_ = pr_[lane + 64 * kk_];                                       \
        float4 xv_ = x4[(P) * 256 + lane + 64 * kk_];                            \
        bvacc += pv_.x * xv_.x + pv_.y * xv_.y + pv_.z * xv_.z + pv_.w * xv_.w;  \
    }                                                                            \
    __syncthreads(); }

    BVP(0) BVP(1) BVP(2) BVP(3)
#undef BVP

    // chunks 4..7 (j >= I_SZ): symmetrize into named regs (static indices only)
#define SYM(K, KK) {                                                             \
    const float4* pr_ = (const float4*)(&panT[wave][0]);                         \
    float4 pv_ = pr_[lane + 64 * (KK)];                                          \
    w##K.x = 0.5f * (w##K.x + pv_.x); w##K.y = 0.5f * (w##K.y + pv_.y);          \
    w##K.z = 0.5f * (w##K.z + pv_.z); w##K.w = 0.5f * (w##K.w + pv_.w); }
#define SYMP(P, K0, K1, K2, K3) PANEL(P)                                         \
    SYM(K0, 0) SYM(K1, 1) SYM(K2, 2) SYM(K3, 3)                                  \
    __syncthreads();

    SYMP(4, 0, 1, 2, 3)
    SYMP(5, 4, 5, 6, 7)
    SYMP(6, 8, 9, 10, 11)
    SYMP(7, 12, 13, 14, 15)
#undef SYMP
#undef SYM
#undef PANEL

    // ---- bv = 0.5*(b1 + b2): reduce across lanes (lane 0 holds it) ----
    for (int off = 32; off > 0; off >>= 1) bvacc += __shfl_down(bvacc, off, 64);
    const float bv = 0.5f * bvacc;

    const float ts  = tsum[0];
    const float tev = (row >= H_SZ) ? te[row - H_SZ] : 0.0f;

    // ---- iteration 0: s_tail = 0 -> g = bv, s_row = 0 (no staging, no dot) ----
    if (lane == 0) {
        float nv = tanhf(-LR * bv);
        __hip_atomic_store(&s_b[I_SZ + row], nv, __ATOMIC_RELAXED,
                           __HIP_MEMORY_SCOPE_AGENT);
    }
    grid_barrier(bar, blk, tid, 1u);

    for (int it = 1; it < T1C + T2C; ++it) {
        const float* cur = (it & 1) ? s_b : s_a;
        float*       nxt = (it & 1) ? s_a : s_b;
        const bool betap = (it >= T1C);

        // ---- stage s_tail -> LDS through the coherence point (agent-scope 8B loads)
        const unsigned long long* cu = (const unsigned long long*)(cur + I_SZ);
        unsigned long long* shu = (unsigned long long*)sh;
        #pragma unroll
        for (int m = 0; m < 2; ++m) {
            int idx = tid + NTHR * m;         // < 2048
            shu[idx] = __hip_atomic_load(&cu[idx], __ATOMIC_RELAXED,
                                         __HIP_MEMORY_SCOPE_AGENT);
        }
        __syncthreads();

        const float4* sh4 = (const float4*)sh;

        // ---- wave-local redundant softmax stats (beta phase, output-row blocks only)
        float sm_m = 0.f, sm_z = 1.f;
        if (betap && out_block) {
            float4 l0 = sh4[H_SZ / 4 + lane];
            float4 l1 = sh4[H_SZ / 4 + 64 + lane];
            float m = fmaxf(fmaxf(fmaxf(l0.x, l0.y), fmaxf(l0.z, l0.w)),
                            fmaxf(fmaxf(l1.x, l1.y), fmaxf(l1.z, l1.w)));
            for (int off = 32; off > 0; off >>= 1) m = fmaxf(m, __shfl_xor(m, off, 64));
            float z = expf(l0.x - m) + expf(l0.y - m) + expf(l0.z - m) + expf(l0.w - m)
                    + expf(l1.x - m) + expf(l1.y - m) + expf(l1.z - m) + expf(l1.w - m);
            for (int off = 32; off > 0; off >>= 1) z += __shfl_xor(z, off, 64);
            sm_m = m; sm_z = z;
        }

        // ---- one wave per row: 4096-wide dot, row in named VGPRs, s from LDS ----
        float acc = 0.0f;
#define DOT(K) { float4 s_ = sh4[lane + 64 * (K)];                               \
    acc += w##K.x * s_.x + w##K.y * s_.y + w##K.z * s_.z + w##K.w * s_.w; }
        DOT(0)  DOT(1)  DOT(2)  DOT(3)
        DOT(4)  DOT(5)  DOT(6)  DOT(7)
        DOT(8)  DOT(9)  DOT(10) DOT(11)
        DOT(12) DOT(13) DOT(14) DOT(15)
#undef DOT
        for (int off = 32; off > 0; off >>= 1) acc += __shfl_down(acc, off, 64);
        if (lane == 0) {
            float g = acc + bv;
            if (betap && row >= H_SZ) {
                float p = expf(sh[row] - sm_m) / sm_z;
                g += -BETA * (p * ts - tev);
            }
            float nv = tanhf(sh[row] - LR * g);
            __hip_atomic_store(&nxt[I_SZ + row], nv, __ATOMIC_RELAXED,
                               __HIP_MEMORY_SCOPE_AGENT);
        }

        // ---- last iteration: stores drain at kernel end; no consumer inside ----
        if (it == T1C + T2C - 1) break;
        grid_barrier(bar, blk, tid, (unsigned int)(it + 1));
    }
}

// ================= fallback path (only if cooperative launch fails) =================
__global__ void k_init_fb(const float* __restrict__ x, float* __restrict__ s_a,
                          float* __restrict__ s_b, unsigned int* __restrict__ bar) {
    int i = blockIdx.x * 256 + threadIdx.x;
    if (i < I_SZ) { float v = x[i]; s_a[i] = v; s_b[i] = v; }
    else if (i < TOTAL) { s_a[i] = 0.0f; }
    if (i < 1024) bar[i] = 0u;
}

__global__ void k_build_wt(const float* __restrict__ W, float* __restrict__ Wt) {
    int bj = blockIdx.x, bi = blockIdx.y;
    if (bi > bj) return;
    __shared__ float ta[32][33], tb[32][33];
    int tx = threadIdx.x;
    int ty = threadIdx.y;
    int r0 = bi * 32, c0 = bj * 32;
    #pragma unroll
    for (int k = 0; k < 4; k++) {
        int a = ty + 8 * k;
        ta[a][tx] = W[(size_t)(I_SZ + r0 + a) * TOTAL + (I_SZ + c0 + tx)];
    }
    if (bi != bj) {
        #pragma unroll
        for (int k = 0; k < 4; k++) {
            int a = ty + 8 * k;
            tb[a][tx] = W[(size_t)(I_SZ + c0 + a) * TOTAL + (I_SZ + r0 + tx)];
        }
    }
    __syncthreads();
    if (bi == bj) {
        #pragma unroll
        for (int k = 0; k < 4; k++) {
            int a = ty + 8 * k;
            Wt[(size_t)(r0 + a) * HO + (c0 + tx)] = 0.5f * (ta[a][tx] + ta[tx][a]);
        }
    } else {
        #pragma unroll
        for (int k = 0; k < 4; k++) {
            int a = ty + 8 * k;
            Wt[(size_t)(r0 + a) * HO + (c0 + tx)] = 0.5f * (ta[a][tx] + tb[tx][a]);
            Wt[(size_t)(c0 + a) * HO + (r0 + tx)] = 0.5f * (tb[a][tx] + ta[tx][a]);
        }
    }
}

__global__ void k_build_b1(const float* __restrict__ W, const float* __restrict__ x,
                           float* __restrict__ bvec) {
    int r = blockIdx.x;
    int t = threadIdx.x;
    const float4* wrow = (const float4*)(W + (size_t)(I_SZ + r) * TOTAL);
    const float4* xv   = (const float4*)x;
    float acc = 0.0f;
    #pragma unroll
    for (int k = 0; k < 4; k++) {
        int idx = t + 256 * k;
        float4 w  = wrow[idx];
        float4 s4 = xv[idx];
        acc += w.x * s4.x + w.y * s4.y + w.z * s4.z + w.w * s4.w;
    }
    __shared__ float red[4];
    for (int off = 32; off > 0; off >>= 1) acc += __shfl_down(acc, off, 64);
    if ((t & 63) == 0) red[t >> 6] = acc;
    __syncthreads();
    if (t == 0) bvec[r] = 0.5f * (red[0] + red[1] + red[2] + red[3]);
}

__global__ void k_build_b2(const float* __restrict__ W, const float* __restrict__ x,
                           float* __restrict__ bvec) {
    int c  = blockIdx.x * 256 + threadIdx.x;
    int j0 = blockIdx.y * 64;
    float acc = 0.0f;
    for (int j = j0; j < j0 + 64; j++)
        acc += W[(size_t)j * TOTAL + (I_SZ + c)] * x[j];
    atomicAdd(&bvec[c], 0.5f * acc);
}

template <bool BETA_STEP>
__global__ void __launch_bounds__(256, 4) k_step4(
    const float* __restrict__ Wt, const float* __restrict__ bvec,
    const float* __restrict__ s_cur, float* __restrict__ s_next,
    const float* __restrict__ te, const float* __restrict__ tsum)
{
    const int blk  = blockIdx.x;
    const int t    = threadIdx.x;
    const int wave = t >> 6;
    const int lane = t & 63;
    const int row  = blk * 4 + wave;

    __shared__ float red[4];
    __shared__ float sm_m, sm_z;

    if (BETA_STEP && blk >= H_SZ / 4) {
        float l0 = s_cur[I_SZ + H_SZ + t];
        float l1 = s_cur[I_SZ + H_SZ + t + 256];
        float m = fmaxf(l0, l1);
        for (int off = 32; off > 0; off >>= 1) m = fmaxf(m, __shfl_down(m, off, 64));
        if (lane == 0) red[wave] = m;
        __syncthreads();
        if (t == 0) sm_m = fmaxf(fmaxf(red[0], red[1]), fmaxf(red[2], red[3]));
        __syncthreads();
        float z = expf(l0 - sm_m) + expf(l1 - sm_m);
        for (int off = 32; off > 0; off >>= 1) z += __shfl_down(z, off, 64);
        if (lane == 0) red[wave] = z;
        __syncthreads();
        if (t == 0) sm_z = red[0] + red[1] + red[2] + red[3];
        __syncthreads();
    }

    const float4* w4 = (const float4*)(Wt + (size_t)row * HO);
    const float4* s4 = (const float4*)(s_cur + I_SZ);
    float4 w[16];
    #pragma unroll
    for (int k = 0; k < 16; k++) w[k] = w4[lane + 64 * k];
    float acc = 0.0f;
    #pragma unroll
    for (int k = 0; k < 16; k++) {
        float4 s = s4[lane + 64 * k];
        acc += w[k].x * s.x + w[k].y * s.y + w[k].z * s.z + w[k].w * s.w;
    }
    for (int off = 32; off > 0; off >>= 1) acc += __shfl_down(acc, off, 64);
    if (lane == 0) {
        float g = acc + bvec[row];
        if (BETA_STEP && row >= H_SZ) {
            int j = row - H_SZ;
            float p = expf(s_cur[I_SZ + H_SZ + j] - sm_m) / sm_z;
            g += -BETA * (p * tsum[0] - te[j]);
        }
        int i = I_SZ + row;
        s_next[i] = tanhf(s_cur[i] - LR * g);
    }
}

extern "C" void kernel_launch(void* const* d_in, const int* in_sizes, int n_in,
                              void* d_out, int out_size, void* d_ws, size_t ws_size,
                              hipStream_t stream) {
    const float* W      = (const float*)d_in[0];
    const float* x      = (const float*)d_in[1];
    const float* target = (const float*)d_in[2];
    const float* mask   = (const float*)d_in[3];
    float* out = (float*)d_out;   // state buffer A (24 steps even -> final lands here)
    char*  ws  = (char*)d_ws;

    const size_t WS_WT = (size_t)HO * HO * sizeof(float);   // 64 MB (fallback only)
    float*        Wt   = (float*)ws;
    float*        bvec = (float*)(ws + WS_WT);
    float*        te   = bvec + HO;
    float*        tsum = te + O_SZ;
    float*        s_b  = tsum + 64;
    unsigned int* bar  = (unsigned int*)(s_b + TOTAL + 64);

    k_pre<<<1, 1024, 0, stream>>>(x, target, mask, out, te, tsum, bar);

    void* args[] = { (void*)&W, (void*)&x, (void*)&te, (void*)&tsum,
                     (void*)&out, (void*)&s_b, (void*)&bar };
    hipError_t err = hipLaunchCooperativeKernel((const void*)k_run, dim3(NBLK), dim3(NTHR),
                                                args, 0, stream);
    if (err != hipSuccess) {
        // fallback: known-good multi-dispatch chain
        k_init_fb<<<(TOTAL + 255) / 256, 256, 0, stream>>>(x, out, s_b, bar);
        k_build_wt<<<dim3(HO / 32, HO / 32), dim3(32, 8), 0, stream>>>(W, Wt);
        k_build_b1<<<HO, 256, 0, stream>>>(W, x, bvec);
        k_build_b2<<<dim3(HO / 256, I_SZ / 64), 256, 0, stream>>>(W, x, bvec);
        const float* cur = out;
        float* nxt = s_b;
        for (int it = 0; it < T1C + T2C; it++) {
            if (it >= T1C) {
                k_step4<true><<<HO / 4, 256, 0, stream>>>(Wt, bvec, cur, nxt, te, tsum);
            } else {
                k_step4<false><<<HO / 4, 256, 0, stream>>>(Wt, bvec, cur, nxt, te, tsum);
            }
            float* tmp = (float*)cur; cur = nxt; nxt = tmp;
        }
    }
}